// Round 13
// baseline (3527.848 us; speedup 1.0000x reference)
//
#include <hip/hip_runtime.h>

#define DIM 64
#define RPW 13               // rows per wave (LDS accumulator rows)
#define TILE_SHIFT 13        // 8192 cols/tile = 2 MB x-slice (fits 4 MB XCD L2)
#define SCAN_ELEMS 2048      // elements per scan block (256 thr x 8)
#define NPB 1024             // partition blocks (pcount/pscatter)
#define KPB 128              // keys per bucket (bucket = key>>7)
#define BCAP 8192            // bucket LDS stage cap (mean 4092, +64 sigma)

typedef unsigned long long u64;

// ---------------------------------------------------------------------------
// LightGCN: 3 x (y[row] += val * x[col]) over COO edges (NNZ=3.2M, N=100k).
//
// r12 post-mortem: col-tiling halved FETCH (360->170MB) but the per-row
// while-loop serialized gathers (1 in flight, ~1245 cy/edge) -> 216us.
// This round: keep tiling, restore r9's 4-deep MLP via a FLAT unrolled loop:
//   - key = (col>>13)*nw + row/13  (tile, wave) — run is wave-private
//   - record packs ri = row%13 (4b) so the acc row is data, not control
//   - accumulate with LDS atomicAdd (ds_add_f32: no return, in-order per
//     wave, addr = ri*256+lane*4 -> 2 lanes/bank = conflict-free)
//   - 4 independent gathers in flight per wave, hitting L2 (tiled)
// Record: [63:32]=val, [27:21]=key&127, [20:17]=ri, [16:0]=col (N<2^17).
// Build: counting sort over 100k keys / 782 buckets (LDS atomics only),
// same measured pcount->scan->pscatter->bucket-finalize structure.
// ws ~55 MB (proven >= 78.5 in r9).
// ---------------------------------------------------------------------------

// ---------------- build: partition count over nbuck buckets ----------------

__global__ __launch_bounds__(256) void k_pcount2(
    const int* __restrict__ rows, const int* __restrict__ cols,
    int* __restrict__ bc, int nnz, int nw, int nbuck, int epb)
{
    __shared__ int h[800];
    const int b = blockIdx.x;
    for (int i = threadIdx.x; i < nbuck; i += 256) h[i] = 0;
    __syncthreads();
    const int e0 = b * epb;
    const int e1 = (e0 + epb < nnz) ? e0 + epb : nnz;
    for (int e = e0 + threadIdx.x; e < e1; e += 256) {
        const int r = __builtin_nontemporal_load(rows + e);
        const int c = __builtin_nontemporal_load(cols + e);
        const int key = (c >> TILE_SHIFT) * nw + r / RPW;
        atomicAdd(&h[key >> 7], 1);
    }
    __syncthreads();
    for (int k = threadIdx.x; k < nbuck; k += 256)
        bc[k * NPB + b] = h[k];
}

// ---------------- scan stack (measured; scan1 in-place safe) ----------------

__global__ __launch_bounds__(256) void k_scan1(const int* counts, int* rp,
                                               int* blocksums, int n)
{
    __shared__ int lds[256];
    const int t = threadIdx.x, b = blockIdx.x;
    const int base = b * SCAN_ELEMS + t * 8;
    int v[8], s = 0;
#pragma unroll
    for (int k = 0; k < 8; ++k) {
        const int idx = base + k;
        v[k] = (idx < n) ? counts[idx] : 0;
        s += v[k];
    }
    lds[t] = s;
    __syncthreads();
    for (int off = 1; off < 256; off <<= 1) {
        const int val = (t >= off) ? lds[t - off] : 0;
        __syncthreads();
        lds[t] += val;
        __syncthreads();
    }
    const int incl = lds[t];
    if (t == 255) blocksums[b] = incl;
    int run = incl - s;
#pragma unroll
    for (int k = 0; k < 8; ++k) {
        const int idx = base + k;
        if (idx < n) rp[idx] = run;
        run += v[k];
    }
}

// single-block exclusive scan of up to 1024 block sums (need 391)
__global__ __launch_bounds__(256) void k_scan2_big(int* __restrict__ bs, int nb)
{
    __shared__ int lds[256];
    const int t = threadIdx.x;
    int v[4], s = 0;
#pragma unroll
    for (int k = 0; k < 4; ++k) {
        const int i = t * 4 + k;
        v[k] = (i < nb) ? bs[i] : 0;
        s += v[k];
    }
    lds[t] = s;
    __syncthreads();
    for (int off = 1; off < 256; off <<= 1) {
        const int val = (t >= off) ? lds[t - off] : 0;
        __syncthreads();
        lds[t] += val;
        __syncthreads();
    }
    int run = lds[t] - s;
#pragma unroll
    for (int k = 0; k < 4; ++k) {
        const int i = t * 4 + k;
        if (i < nb) bs[i] = run;
        run += v[k];
    }
}

__global__ __launch_bounds__(256) void k_scan3(int* __restrict__ rp,
                                               const int* __restrict__ blocksums,
                                               int n, int nnz)
{
    for (int i = blockIdx.x * blockDim.x + threadIdx.x; i < n;
         i += gridDim.x * blockDim.x) {
        rp[i] = rp[i] + blocksums[i / SCAN_ELEMS];
        if (i == 0) rp[n] = nnz;
    }
}

// ---------------- build: partition scatter ----------------

__global__ __launch_bounds__(256) void k_pscatter2(
    const int* __restrict__ rows, const int* __restrict__ cols,
    const float* __restrict__ vals, const int* __restrict__ bc,
    u64* __restrict__ packed, int nnz, int nw, int nbuck, int epb)
{
    __shared__ int cur[800];
    const int b = blockIdx.x;
    for (int k = threadIdx.x; k < nbuck; k += 256) cur[k] = bc[k * NPB + b];
    __syncthreads();
    const int e0 = b * epb;
    const int e1 = (e0 + epb < nnz) ? e0 + epb : nnz;
    for (int e = e0 + threadIdx.x; e < e1; e += 256) {
        const int r = __builtin_nontemporal_load(rows + e);
        const int c = __builtin_nontemporal_load(cols + e);
        const float v = __builtin_nontemporal_load(vals + e);
        const int wv = r / RPW;
        const int key = (c >> TILE_SHIFT) * nw + wv;
        const int ri = r - wv * RPW;
        const int p = atomicAdd(&cur[key >> 7], 1);     // LDS atomic
        packed[p] = ((u64)(unsigned)__float_as_int(v) << 32)
                  | ((u64)(unsigned)(key & 127) << 21)
                  | ((u64)(unsigned)ri << 17)
                  | (u64)(unsigned)c;
    }
}

// ---------------- build: per-bucket finalize (IN-PLACE via LDS stage) ------

__global__ __launch_bounds__(256) void k_bucket_csr2(
    u64* __restrict__ packed,            // in: bucket-partitioned; out: key-sorted
    const int* __restrict__ bc,          // scanned partition matrix
    int* __restrict__ rp2,               // out: per-key starts (ktot+1)
    int nnz, int nbuck, int ktot)
{
    __shared__ u64 stage[BCAP];
    __shared__ int hist[128];
    __shared__ int scanb[128];
    const int kb = blockIdx.x;
    const int t = threadIdx.x;
    const int bstart = bc[kb * NPB];
    const int bend = (kb + 1 < nbuck) ? bc[(kb + 1) * NPB] : nnz;
    int cnt = bend - bstart;
    if (cnt > BCAP) cnt = BCAP;          // +64 sigma, untriggerable here
    for (int i = t; i < cnt; i += 256)
        stage[i] = __builtin_nontemporal_load(packed + bstart + i);
    if (t < 128) hist[t] = 0;
    __syncthreads();
    for (int i = t; i < cnt; i += 256)
        atomicAdd(&hist[(int)((stage[i] >> 21) & 127)], 1);
    __syncthreads();
    if (t < 128) scanb[t] = hist[t];
    __syncthreads();
    for (int off = 1; off < 128; off <<= 1) {
        const int v = (t < 128 && t >= off) ? scanb[t - off] : 0;
        __syncthreads();
        if (t < 128) scanb[t] += v;
        __syncthreads();
    }
    int excl = 0;
    if (t < 128) excl = scanb[t] - hist[t];   // exclusive prefix
    __syncthreads();
    if (t < 128) {
        hist[t] = excl;                        // cursors
        const int g = (kb << 7) + t;
        if (g < ktot) rp2[g] = bstart + excl;
    }
    if (kb == 0 && t == 0) rp2[ktot] = nnz;
    __syncthreads();
    // scatter from LDS stage to final position (record kept as-is)
    for (int i = t; i < cnt; i += 256) {
        const u64 rec = stage[i];
        const int bin = (int)((rec >> 21) & 127);
        const int p = bstart + atomicAdd(&hist[bin], 1);   // LDS atomic
        packed[p] = rec;
    }
}

// ---------------- col-tiled SpMM with LDS accumulators ----------------
// Flat 4-unrolled loop over the wave's (tile) run: 4 independent L2 gathers
// in flight; accumulate via ds_add_f32 into wave-private LDS (13 rows x 64).

__global__ __launch_bounds__(256) void k_spmm_lds(
    const float* __restrict__ x, const int* __restrict__ rp2,
    const u64* __restrict__ edges, float* __restrict__ y,
    int n, int nw, int nt)
{
    __shared__ float sacc[4 * RPW * DIM];
    const int lane = threadIdx.x & 63;
    const int wib  = threadIdx.x >> 6;
    const int w = (blockIdx.x * blockDim.x + threadIdx.x) >> 6;
    if (w >= nw) return;
    float* acc = sacc + wib * (RPW * DIM);
#pragma unroll
    for (int i = 0; i < RPW; ++i) acc[i * DIM + lane] = 0.f;
    const int r0 = w * RPW;

    for (int t = 0; t < nt; ++t) {
        const int key = t * nw + w;
        const int j0   = __builtin_amdgcn_readfirstlane(rp2[key]);
        const int jend = __builtin_amdgcn_readfirstlane(rp2[key + 1]);
        for (int j = j0; j < jend; j += 64) {
            const int nn = (jend - j < 64) ? (jend - j) : 64;
            const u64 rec = __builtin_nontemporal_load(
                edges + j + ((lane < nn) ? lane : 0));
            const int lo = (int)(unsigned)(rec & 0xffffffffu);
            const int hi = (int)(unsigned)(rec >> 32);
            int k = 0;
            for (; k + 4 <= nn; k += 4) {
                const int l0 = __builtin_amdgcn_readlane(lo, k + 0);
                const int h0 = __builtin_amdgcn_readlane(hi, k + 0);
                const int l1 = __builtin_amdgcn_readlane(lo, k + 1);
                const int h1 = __builtin_amdgcn_readlane(hi, k + 1);
                const int l2 = __builtin_amdgcn_readlane(lo, k + 2);
                const int h2 = __builtin_amdgcn_readlane(hi, k + 2);
                const int l3 = __builtin_amdgcn_readlane(lo, k + 3);
                const int h3 = __builtin_amdgcn_readlane(hi, k + 3);
                const float xv0 = x[(size_t)(l0 & 0x1FFFF) * DIM + lane];
                const float xv1 = x[(size_t)(l1 & 0x1FFFF) * DIM + lane];
                const float xv2 = x[(size_t)(l2 & 0x1FFFF) * DIM + lane];
                const float xv3 = x[(size_t)(l3 & 0x1FFFF) * DIM + lane];
                atomicAdd(&acc[((l0 >> 17) & 15) * DIM + lane],
                          __int_as_float(h0) * xv0);
                atomicAdd(&acc[((l1 >> 17) & 15) * DIM + lane],
                          __int_as_float(h1) * xv1);
                atomicAdd(&acc[((l2 >> 17) & 15) * DIM + lane],
                          __int_as_float(h2) * xv2);
                atomicAdd(&acc[((l3 >> 17) & 15) * DIM + lane],
                          __int_as_float(h3) * xv3);
            }
            for (; k < nn; ++k) {
                const int l = __builtin_amdgcn_readlane(lo, k);
                const int h = __builtin_amdgcn_readlane(hi, k);
                const float xv = x[(size_t)(l & 0x1FFFF) * DIM + lane];
                atomicAdd(&acc[((l >> 17) & 15) * DIM + lane],
                          __int_as_float(h) * xv);
            }
        }
    }
#pragma unroll
    for (int i = 0; i < RPW; ++i) {
        const int r = r0 + i;
        if (r < n) y[(size_t)r * DIM + lane] = acc[i * DIM + lane];
    }
}

// ---------------- fallback: per-edge atomic (defensive only) ----------------

__global__ __launch_bounds__(256) void lgcn_atomic(
    const float* __restrict__ x, const float* __restrict__ vals,
    const int* __restrict__ rows, const int* __restrict__ cols,
    float* __restrict__ y, int nnz, int edges_per_wave)
{
    const int lane = threadIdx.x & 63;
    const int wid = (blockIdx.x * blockDim.x + threadIdx.x) >> 6;
    int e0 = wid * edges_per_wave, e1 = e0 + edges_per_wave;
    if (e1 > nnz) e1 = nnz;
    for (int e = e0; e < e1; ++e) {
        const int eu = __builtin_amdgcn_readfirstlane(e);
        const float v = vals[eu];
        const float xv = x[(size_t)cols[eu] * DIM + lane];
        unsafeAtomicAdd(y + (size_t)rows[eu] * DIM + lane, v * xv);
    }
}

// ---------------- host ----------------

static inline size_t align256(size_t x) { return (x + 255) & ~(size_t)255; }

extern "C" void kernel_launch(void* const* d_in, const int* in_sizes, int n_in,
                              void* d_out, int out_size, void* d_ws, size_t ws_size,
                              hipStream_t stream)
{
    const float* user_emb = (const float*)d_in[0];
    const float* item_emb = (const float*)d_in[1];
    const float* vals     = (const float*)d_in[2];
    const int*   rows     = (const int*)d_in[3];
    const int*   cols     = (const int*)d_in[4];
    float*       out      = (float*)d_out;

    const int n   = (in_sizes[0] + in_sizes[1]) / DIM;   // n_nodes = 100k
    const int nnz = in_sizes[2];

    const size_t u_bytes = (size_t)in_sizes[0] * sizeof(float);
    const size_t i_bytes = (size_t)in_sizes[1] * sizeof(float);
    const size_t x_bytes = (size_t)n * DIM * sizeof(float);
    const size_t e_bytes = (size_t)nnz * sizeof(u64);

    const int nt    = (n + (1 << TILE_SHIFT) - 1) >> TILE_SHIFT;   // 13
    const int nw    = (n + RPW - 1) / RPW;                         // 7693 waves
    const int ktot  = nt * nw;                                     // 100,009
    const int nbuck = (ktot + KPB - 1) / KPB;                      // 782
    const int n2    = nbuck * NPB;                                 // 800,768
    const int nsb   = (n2 + SCAN_ELEMS - 1) / SCAN_ELEMS;          // 391 <= 1024
    const int epb   = (nnz + NPB - 1) / NPB;                       // 3125

    // ws layout (~55 MB; >= 78.5 MB proven available in r9)
    size_t off = 0;
    float* x_mid  = (float*)((char*)d_ws + off); off += align256(x_bytes);
    u64*   packed = (u64*)  ((char*)d_ws + off); off += align256(e_bytes);
    int*   rp2    = (int*)  ((char*)d_ws + off); off += align256(((size_t)ktot + 1) * sizeof(int));
    int*   bc     = (int*)  ((char*)d_ws + off); off += align256(((size_t)n2 + 256) * sizeof(int));
    int*   bsums  = (int*)  ((char*)d_ws + off); off += align256((size_t)1024 * sizeof(int));
    const size_t need = off;

    const int blocks = 2048, threads = 256;

    // x0 = concat(user_emb, item_emb) -> x_mid
    hipMemcpyAsync(x_mid, user_emb, u_bytes, hipMemcpyDeviceToDevice, stream);
    hipMemcpyAsync((char*)x_mid + u_bytes, item_emb, i_bytes,
                   hipMemcpyDeviceToDevice, stream);

    if (ws_size >= need) {
        // ---- build: counting sort by key=(col>>13)*nw + row/13 ----
        k_pcount2<<<NPB, threads, 0, stream>>>(rows, cols, bc, nnz, nw, nbuck, epb);
        k_scan1<<<nsb, 256, 0, stream>>>(bc, bc, bsums, n2);        // in-place
        k_scan2_big<<<1, 256, 0, stream>>>(bsums, nsb);
        k_scan3<<<blocks, threads, 0, stream>>>(bc, bsums, n2, nnz);
        k_pscatter2<<<NPB, threads, 0, stream>>>(rows, cols, vals, bc, packed,
                                                 nnz, nw, nbuck, epb);
        k_bucket_csr2<<<nbuck, threads, 0, stream>>>(packed, bc, rp2,
                                                     nnz, nbuck, ktot);
        // ---- 3 col-tiled SpMM layers ----
        const int sb = (nw + 3) / 4;                   // 1924 blocks
        k_spmm_lds<<<sb, threads, 0, stream>>>(x_mid, rp2, packed, out, n, nw, nt);
        k_spmm_lds<<<sb, threads, 0, stream>>>(out, rp2, packed, x_mid, n, nw, nt);
        k_spmm_lds<<<sb, threads, 0, stream>>>(x_mid, rp2, packed, out, n, nw, nt);
    } else {
        // ---- defensive fallback: per-edge atomic ----
        const int nwaves = blocks * (threads / 64);
        const int epw = (nnz + nwaves - 1) / nwaves;
        hipMemsetAsync(out, 0, x_bytes, stream);
        lgcn_atomic<<<blocks, threads, 0, stream>>>(x_mid, vals, rows, cols, out,
                                                    nnz, epw);
        hipMemsetAsync(x_mid, 0, x_bytes, stream);
        lgcn_atomic<<<blocks, threads, 0, stream>>>(out, vals, rows, cols, x_mid,
                                                    nnz, epw);
        hipMemsetAsync(out, 0, x_bytes, stream);
        lgcn_atomic<<<blocks, threads, 0, stream>>>(x_mid, vals, rows, cols, out,
                                                    nnz, epw);
    }
}